// Round 10
// baseline (659.354 us; speedup 1.0000x reference)
//
#include <hip/hip_runtime.h>
#include <stdint.h>

#define HH 200
#define WW 200
#define HWSZ 40000
#define NPX 80000

typedef __attribute__((ext_vector_type(8))) short bf16x8;
typedef __attribute__((ext_vector_type(4))) float f32x4;

// counted vmcnt wait (no drain-to-0 in steady state); barrier via builtin.
// NOTE: no lgkmcnt drains in the K-loops -- the compiler's fine-grained
// lgkmcnt between ds_read and consuming MFMA overlaps the LDS queue with
// the MFMA burst (hand LGKM_WAIT0 before MFMA was costing ~1500 cy/step).
#define VM_WAIT(N) asm volatile("s_waitcnt vmcnt(" #N ")" ::: "memory")
#define BARRIER()  __builtin_amdgcn_s_barrier()

__device__ __forceinline__ float bf2f(unsigned short u) {
    union { uint32_t i; float f; } c; c.i = ((uint32_t)u) << 16; return c.f;
}
__device__ __forceinline__ unsigned short f2bf(float f) {
    union { float f; uint32_t i; } c; c.f = f;
    uint32_t r = c.i + 0x7FFF + ((c.i >> 16) & 1);   // RNE
    return (unsigned short)(r >> 16);
}
__device__ __forceinline__ unsigned int cvtpk_bf16(float lo, float hi) {
    unsigned int r;
    asm("v_cvt_pk_bf16_f32 %0, %1, %2" : "=v"(r) : "v"(lo), "v"(hi));
    return r;
}
__device__ __forceinline__ void gload16(const void* g, void* l) {
    __builtin_amdgcn_global_load_lds(
        (const __attribute__((address_space(1))) unsigned int*)g,
        (__attribute__((address_space(3))) unsigned int*)l, 16, 0, 0);
}

// ---------------------------------------------------------------------------
// Weight conversion: fp32 -> bf16. Wkv = [Wk; Wv] rows (512 x 256);
// Wcat = concat(Wo, Wr) along k; W1/W2 transposed to [cout][cin].
// ---------------------------------------------------------------------------
__global__ __launch_bounds__(256) void cvt_weights(
    const float* __restrict__ Wq, const float* __restrict__ Wk,
    const float* __restrict__ Wv, const float* __restrict__ Wo,
    const float* __restrict__ Wr, const float* __restrict__ W1,
    const float* __restrict__ W2,
    unsigned short* Wq_b, unsigned short* Wkv_b,
    unsigned short* Wcat, unsigned short* W1t, unsigned short* W2t)
{
    const int seg = blockIdx.y;
    const int idx = blockIdx.x * 256 + threadIdx.x;
    if (seg == 0)      { if (idx < 16384) Wq_b[idx] = f2bf(Wq[idx]); }
    else if (seg == 1) {
        if (idx < 131072) {
            int r = idx >> 8, k = idx & 255;
            Wkv_b[idx] = f2bf(r < 256 ? Wk[r * 256 + k] : Wv[(r - 256) * 256 + k]);
        }
    } else if (seg == 2) {
        if (idx < 81920) {
            int r = idx / 320, k = idx - r * 320;
            Wcat[idx] = f2bf(k < 256 ? Wo[r * 256 + k] : Wr[r * 64 + (k - 256)]);
        }
    } else if (seg == 3) {
        if (idx < 262144) { int o = idx >> 8, i = idx & 255; W1t[idx] = f2bf(W1[i * 1024 + o]); }
    } else {
        if (idx < 262144) { int o = idx >> 10, i = idx & 1023; W2t[idx] = f2bf(W2[i * 256 + o]); }
    }
}

// ---------------------------------------------------------------------------
// NCHW fp32 -> NHWC bf16 (64px x 64c LDS tile).
// ---------------------------------------------------------------------------
__global__ __launch_bounds__(256) void to_nhwc(
    const float* __restrict__ src, unsigned short* __restrict__ dst, int C)
{
    __shared__ unsigned short T[64][72];
    const int b = blockIdx.z, c0 = blockIdx.y * 64, px0 = blockIdx.x * 64;
    const int t = threadIdx.x;
    const int pxl = t & 63, cl0 = t >> 6;
    const float* sp = src + ((size_t)(b * C + c0 + cl0)) * HWSZ + px0 + pxl;
    #pragma unroll
    for (int i = 0; i < 16; ++i)
        T[pxl][cl0 + i * 4] = f2bf(sp[(size_t)i * 4 * HWSZ]);
    __syncthreads();
    #pragma unroll
    for (int r = 0; r < 2; ++r) {
        int idx = t + r * 256;
        int p = idx >> 3, cof = (idx & 7) * 8;
        uint4 v = *(const uint4*)&T[p][cof];
        *(uint4*)(dst + ((size_t)(b * HWSZ + px0 + p)) * C + c0 + cof) = v;
    }
}

// ---------------------------------------------------------------------------
// bf16 MFMA GEMM, tile 128x128, BK=32, counted-vmcnt double buffer.
// K-loop: VM_WAIT(4)+barrier (tile s in LDS) -> ds_read+MFMA (compiler
// fine-interleaves lgkmcnt) -> barrier (all reads done) -> STAGE(s+2).
// flags: 1=relu, 2=fp32 accumulate, 4=XCD swizzle, 8=split output at 256.
// ---------------------------------------------------------------------------
__global__ __launch_bounds__(256) void gemm_bf16(
    const unsigned short* __restrict__ In, int inStride,
    const unsigned short* __restrict__ In2, int in2Stride, int K1,
    const unsigned short* __restrict__ Wb, int wStride, int Ktot,
    unsigned short* __restrict__ OutB, unsigned short* __restrict__ OutB2,
    float* __restrict__ OutF,
    const float* __restrict__ bias, int flags, int outStride)
{
    __shared__ bf16x8 AB[2][1024];   // per buf: [0..511] A, [512..1023] B
    const int t = threadIdx.x;
    int bx = blockIdx.x, by = blockIdx.y;
    if (flags & 4) {
        const int nxy = gridDim.x * gridDim.y;
        const int flat = blockIdx.x + gridDim.x * blockIdx.y;
        const int qq = nxy >> 3, rr = nxy & 7;
        const int xcd = flat & 7, idx = flat >> 3;
        const int w2 = (xcd < rr ? xcd * (qq + 1)
                                 : rr * (qq + 1) + (xcd - rr) * qq) + idx;
        by = w2 % gridDim.y;
        bx = w2 / gridDim.y;
    }
    const int px0 = bx * 128;
    const int n0 = by * 128;
    const int lane = t & 63, w = t >> 6;
    const int mh = w & 1, nh = w >> 1;

    f32x4 acc[4][4] = {};

    auto STAGE = [&](int buf, int k0s) {   // 4 gload16 per thread
        #pragma unroll
        for (int r = 0; r < 2; ++r) {
            const int c = t + r * 256;
            const int l = c & 63;
            const int ko = k0s + ((l >> 4) << 3);
            const int mt = c >> 6;
            {
                const int px = px0 + mt * 16 + (l & 15);
                const unsigned short* sp = (ko < K1)
                    ? (In  + (size_t)px * inStride  + ko)
                    : (In2 + (size_t)px * in2Stride + (ko - K1));
                gload16(sp, &AB[buf][c]);
            }
            {
                const int cc = n0 + mt * 16 + (l & 15);
                gload16(Wb + (size_t)cc * wStride + ko, &AB[buf][512 + c]);
            }
        }
    };

    const int nsteps = Ktot >> 5;
    STAGE(0, 0);
    if (nsteps > 1) STAGE(1, 32);
    int cur = 0;

    for (int s = 0; s < nsteps - 1; ++s) {
        VM_WAIT(4);          // tile s landed (s+1 still in flight)
        BARRIER();
        bf16x8 av[4], bv[4];
        #pragma unroll
        for (int i = 0; i < 4; ++i) av[i] = AB[cur][(mh * 4 + i) * 64 + lane];
        #pragma unroll
        for (int j = 0; j < 4; ++j) bv[j] = AB[cur][512 + (nh * 4 + j) * 64 + lane];
        #pragma unroll
        for (int i = 0; i < 4; ++i)
            #pragma unroll
            for (int j = 0; j < 4; ++j)
                acc[i][j] = __builtin_amdgcn_mfma_f32_16x16x32_bf16(
                    av[i], bv[j], acc[i][j], 0, 0, 0);
        BARRIER();           // all waves' reads consumed -> overwrite safe
        if (s + 2 < nsteps) STAGE(cur, (s + 2) * 32);
        cur ^= 1;
    }
    VM_WAIT(0);
    BARRIER();
    {
        bf16x8 av[4], bv[4];
        #pragma unroll
        for (int i = 0; i < 4; ++i) av[i] = AB[cur][(mh * 4 + i) * 64 + lane];
        #pragma unroll
        for (int j = 0; j < 4; ++j) bv[j] = AB[cur][512 + (nh * 4 + j) * 64 + lane];
        #pragma unroll
        for (int i = 0; i < 4; ++i)
            #pragma unroll
            for (int j = 0; j < 4; ++j)
                acc[i][j] = __builtin_amdgcn_mfma_f32_16x16x32_bf16(
                    av[i], bv[j], acc[i][j], 0, 0, 0);
    }

    const int q = lane >> 4, ln = lane & 15;
    const bool relu = (flags & 1) != 0, accum = (flags & 2) != 0;
    const bool split = (flags & 8) != 0;
    #pragma unroll
    for (int i = 0; i < 4; ++i) {
        #pragma unroll
        for (int j = 0; j < 4; ++j) {
            const int coutv = n0 + nh * 64 + j * 16 + ln;
            const float bval = bias ? bias[coutv] : 0.0f;
            #pragma unroll
            for (int r = 0; r < 4; ++r) {
                const int px = px0 + mh * 64 + i * 16 + q * 4 + r;
                float v = acc[i][j][r] + bval;
                if (relu) v = fmaxf(v, 0.0f);
                if (OutB) {
                    if (split && coutv >= 256)
                        OutB2[(size_t)px * outStride + coutv - 256] = f2bf(v);
                    else
                        OutB[(size_t)px * outStride + coutv] = f2bf(v);
                } else {
                    float* op = OutF + (size_t)px * 256 + coutv;
                    if (accum) v += *op;
                    *op = v;
                }
            }
        }
    }
}

// ---------------------------------------------------------------------------
// Fused out-proj + lidar residual + LN1: XLb = LN(concat(A,Fl) x Wcat^T).
// Block = 512 thr, tile 128px x 256 cout (full rows), K=320 (10 steps).
// Same overlap-friendly K-loop as gemm_bf16 (VM_WAIT(3) per tile).
// ---------------------------------------------------------------------------
__global__ __launch_bounds__(512) void proj_ln1(
    const unsigned short* __restrict__ Aq,   // [NPX][256] bf16 (attn out)
    const unsigned short* __restrict__ Fl,   // [NPX][64]  bf16 (lidar)
    const unsigned short* __restrict__ Wcat, // [256][320] bf16
    const float* __restrict__ g1, const float* __restrict__ b1,
    unsigned short* __restrict__ XLb)        // [NPX][256] bf16
{
    __shared__ bf16x8 AB[2][1536];           // 48 KB
    __shared__ float part_s[4][128], part_q[4][128];

    const int t = threadIdx.x;
    const int px0 = blockIdx.x * 128;
    const int lane = t & 63, w = t >> 6;
    const int mh = w & 1, nh = w >> 1;
    const int q = lane >> 4, ln = lane & 15;

    float gv[4], bvv[4];
    #pragma unroll
    for (int j = 0; j < 4; ++j) {
        const int col = nh * 64 + j * 16 + ln;
        gv[j] = g1[col];
        bvv[j] = b1[col];
    }

    f32x4 acc[4][4] = {};

    auto STAGE = [&](int buf, int k0s) {   // 3 gload16 per thread
        #pragma unroll
        for (int r = 0; r < 3; ++r) {
            const int c = t + r * 512;
            const int l = c & 63;
            const int ko = k0s + ((l >> 4) << 3);
            if (c < 512) {                       // A frags (concat)
                const int mt = c >> 6;
                const int px = px0 + mt * 16 + (l & 15);
                const unsigned short* sp = (ko < 256)
                    ? (Aq + (size_t)px * 256 + ko)
                    : (Fl + (size_t)px * 64 + (ko - 256));
                gload16(sp, &AB[buf][c]);
            } else {                             // B frags: 16 n-tiles
                const int c2 = c - 512;
                const int nt = c2 >> 6;
                const int cc = nt * 16 + (l & 15);
                gload16(Wcat + (size_t)cc * 320 + ko, &AB[buf][c]);
            }
        }
    };

    STAGE(0, 0);
    STAGE(1, 32);
    int cur = 0;

    for (int s = 0; s < 9; ++s) {
        VM_WAIT(3);
        BARRIER();
        bf16x8 av[4], bv[4];
        #pragma unroll
        for (int i = 0; i < 4; ++i) av[i] = AB[cur][(mh * 4 + i) * 64 + lane];
        #pragma unroll
        for (int j = 0; j < 4; ++j) bv[j] = AB[cur][512 + (nh * 4 + j) * 64 + lane];
        #pragma unroll
        for (int i = 0; i < 4; ++i)
            #pragma unroll
            for (int j = 0; j < 4; ++j)
                acc[i][j] = __builtin_amdgcn_mfma_f32_16x16x32_bf16(
                    av[i], bv[j], acc[i][j], 0, 0, 0);
        BARRIER();
        if (s + 2 < 10) STAGE(cur, (s + 2) * 32);
        cur ^= 1;
    }
    VM_WAIT(0);
    BARRIER();
    {
        bf16x8 av[4], bv[4];
        #pragma unroll
        for (int i = 0; i < 4; ++i) av[i] = AB[cur][(mh * 4 + i) * 64 + lane];
        #pragma unroll
        for (int j = 0; j < 4; ++j) bv[j] = AB[cur][512 + (nh * 4 + j) * 64 + lane];
        #pragma unroll
        for (int i = 0; i < 4; ++i)
            #pragma unroll
            for (int j = 0; j < 4; ++j)
                acc[i][j] = __builtin_amdgcn_mfma_f32_16x16x32_bf16(
                    av[i], bv[j], acc[i][j], 0, 0, 0);
    }

    // per-pixel LN stats
    #pragma unroll
    for (int i = 0; i < 4; ++i) {
        #pragma unroll
        for (int r = 0; r < 4; ++r) {
            const int pl = mh * 64 + i * 16 + q * 4 + r;
            float s = 0.0f, ssq = 0.0f;
            #pragma unroll
            for (int j = 0; j < 4; ++j) {
                const float v = acc[i][j][r];
                s += v; ssq += v * v;
            }
            #pragma unroll
            for (int o = 1; o <= 8; o <<= 1) {
                s += __shfl_xor(s, o); ssq += __shfl_xor(ssq, o);
            }
            if (ln == 0) { part_s[nh][pl] = s; part_q[nh][pl] = ssq; }
        }
    }
    __syncthreads();

    #pragma unroll
    for (int i = 0; i < 4; ++i) {
        #pragma unroll
        for (int r = 0; r < 4; ++r) {
            const int pl = mh * 64 + i * 16 + q * 4 + r;
            const size_t px = (size_t)px0 + pl;
            const float s  = part_s[0][pl] + part_s[1][pl] + part_s[2][pl] + part_s[3][pl];
            const float sq = part_q[0][pl] + part_q[1][pl] + part_q[2][pl] + part_q[3][pl];
            const float mu = s * (1.0f / 256.0f);
            const float rs = rsqrtf(sq * (1.0f / 256.0f) - mu * mu + 1e-5f);
            #pragma unroll
            for (int j = 0; j < 4; ++j) {
                const int col = nh * 64 + j * 16 + ln;
                XLb[px * 256 + col] = f2bf((acc[i][j][r] - mu) * rs * gv[j] + bvv[j]);
            }
        }
    }
}

// ---------------------------------------------------------------------------
// Fused FFN-2nd-half + LN2: Out = LN(XLb + Y1*W2t + bf2) -> NCHW fp32.
// Same overlap-friendly K-loop (VM_WAIT(3), 32 steps).
// ---------------------------------------------------------------------------
__global__ __launch_bounds__(512) void ffn2_ln2(
    const unsigned short* __restrict__ Y1,
    const unsigned short* __restrict__ XLb,
    const unsigned short* __restrict__ W2t,
    const float* __restrict__ bf2v,
    const float* __restrict__ g2, const float* __restrict__ b2,
    float* __restrict__ Out)
{
    __shared__ union {
        bf16x8 AB[2][1536];
        float  T[256 * 33];
    } sm;
    __shared__ float part_s[4][128], part_q[4][128];

    const int t = threadIdx.x;
    const int px0 = blockIdx.x * 128;
    const int lane = t & 63, w = t >> 6;
    const int mh = w & 1, nh = w >> 1;
    const int q = lane >> 4, ln = lane & 15;

    float biasv[4], gv[4], bvv[4];
    #pragma unroll
    for (int j = 0; j < 4; ++j) {
        const int col = nh * 64 + j * 16 + ln;
        biasv[j] = bf2v[col];
        gv[j] = g2[col];
        bvv[j] = b2[col];
    }

    f32x4 acc[4][4] = {};

    auto STAGE = [&](int buf, int k0s) {
        #pragma unroll
        for (int r = 0; r < 3; ++r) {
            const int c = t + r * 512;
            const int l = c & 63;
            const int ko = k0s + ((l >> 4) << 3);
            if (c < 512) {
                const int mt = c >> 6;
                const int px = px0 + mt * 16 + (l & 15);
                gload16(Y1 + (size_t)px * 1024 + ko, &sm.AB[buf][c]);
            } else {
                const int c2 = c - 512;
                const int nt = c2 >> 6;
                const int cc = nt * 16 + (l & 15);
                gload16(W2t + (size_t)cc * 1024 + ko, &sm.AB[buf][c]);
            }
        }
    };

    STAGE(0, 0);
    STAGE(1, 32);
    int cur = 0;

    for (int s = 0; s < 31; ++s) {
        VM_WAIT(3);
        BARRIER();
        bf16x8 av[4], bv[4];
        #pragma unroll
        for (int i = 0; i < 4; ++i) av[i] = sm.AB[cur][(mh * 4 + i) * 64 + lane];
        #pragma unroll
        for (int j = 0; j < 4; ++j) bv[j] = sm.AB[cur][512 + (nh * 4 + j) * 64 + lane];
        #pragma unroll
        for (int i = 0; i < 4; ++i)
            #pragma unroll
            for (int j = 0; j < 4; ++j)
                acc[i][j] = __builtin_amdgcn_mfma_f32_16x16x32_bf16(
                    av[i], bv[j], acc[i][j], 0, 0, 0);
        BARRIER();
        if (s + 2 < 32) STAGE(cur, (s + 2) * 32);
        cur ^= 1;
    }
    VM_WAIT(0);
    BARRIER();
    {
        bf16x8 av[4], bv[4];
        #pragma unroll
        for (int i = 0; i < 4; ++i) av[i] = sm.AB[cur][(mh * 4 + i) * 64 + lane];
        #pragma unroll
        for (int j = 0; j < 4; ++j) bv[j] = sm.AB[cur][512 + (nh * 4 + j) * 64 + lane];
        #pragma unroll
        for (int i = 0; i < 4; ++i)
            #pragma unroll
            for (int j = 0; j < 4; ++j)
                acc[i][j] = __builtin_amdgcn_mfma_f32_16x16x32_bf16(
                    av[i], bv[j], acc[i][j], 0, 0, 0);
    }

    #pragma unroll
    for (int i = 0; i < 4; ++i) {
        #pragma unroll
        for (int r = 0; r < 4; ++r) {
            const int pl = mh * 64 + i * 16 + q * 4 + r;
            const size_t px = (size_t)px0 + pl;
            float s = 0.0f, ssq = 0.0f;
            #pragma unroll
            for (int j = 0; j < 4; ++j) {
                const int col = nh * 64 + j * 16 + ln;
                float v = acc[i][j][r] + biasv[j] + bf2f(XLb[px * 256 + col]);
                acc[i][j][r] = v;
                s += v; ssq += v * v;
            }
            #pragma unroll
            for (int o = 1; o <= 8; o <<= 1) {
                s += __shfl_xor(s, o); ssq += __shfl_xor(ssq, o);
            }
            if (ln == 0) { part_s[nh][pl] = s; part_q[nh][pl] = ssq; }
        }
    }
    __syncthreads();

    float muv[4][4], rsv[4][4];
    #pragma unroll
    for (int i = 0; i < 4; ++i) {
        #pragma unroll
        for (int r = 0; r < 4; ++r) {
            const int pl = mh * 64 + i * 16 + q * 4 + r;
            const float s  = part_s[0][pl] + part_s[1][pl] + part_s[2][pl] + part_s[3][pl];
            const float sq = part_q[0][pl] + part_q[1][pl] + part_q[2][pl] + part_q[3][pl];
            const float mu = s * (1.0f / 256.0f);
            muv[i][r] = mu;
            rsv[i][r] = rsqrtf(sq * (1.0f / 256.0f) - mu * mu + 1e-5f);
        }
    }
    __syncthreads();

    #pragma unroll
    for (int ck = 0; ck < 4; ++ck) {
        if (mh == (ck >> 1)) {
            const int ib = (ck & 1) * 2;
            #pragma unroll
            for (int ii = 0; ii < 2; ++ii) {
                const int i = ib + ii;
                #pragma unroll
                for (int j = 0; j < 4; ++j) {
                    const int col = nh * 64 + j * 16 + ln;
                    #pragma unroll
                    for (int r = 0; r < 4; ++r) {
                        sm.T[col * 33 + ii * 16 + q * 4 + r] =
                            (acc[i][j][r] - muv[i][r]) * rsv[i][r] * gv[j] + bvv[j];
                    }
                }
            }
        }
        __syncthreads();
        const int pxc = px0 + ck * 32;
        const int bb = pxc / HWSZ;
        const int hw0 = pxc - bb * HWSZ;
        #pragma unroll
        for (int p = 0; p < 16; ++p) {
            const int idx = t + p * 512;
            const int c = idx >> 5, pxl = idx & 31;
            Out[((size_t)(bb * 256 + c)) * HWSZ + hw0 + pxl] = sm.T[c * 33 + pxl];
        }
        __syncthreads();
    }
}

// ---------------------------------------------------------------------------
// 7x7 local-window attention via MFMA (unchanged; XCD swizzle kept).
// ---------------------------------------------------------------------------
__global__ __launch_bounds__(256) void attn_bf16(
    const unsigned short* Q, const unsigned short* __restrict__ K,
    const unsigned short* __restrict__ V, unsigned short* A)
{
    __shared__ __align__(16) unsigned short vt[32 * 536];   // 34304 B
    const int flat = blockIdx.x + 169 * (blockIdx.y + 8 * blockIdx.z);
    const int wsz = (flat & 7) * 338 + (flat >> 3);
    const int tile = wsz >> 4, rem = wsz & 15;
    const int head = rem >> 1, b = rem & 1;
    const int tiy = tile / 13, tix = tile - tiy * 13;
    const int h0 = tiy * 16, w0 = tix * 16;
    const int t = threadIdx.x;
    const int lane = t & 63, wv = t >> 6;
    const int g = lane >> 4, n = lane & 15;
    const int co = head * 32;
    const size_t pxb = (size_t)b * HWSZ;

    for (int idx = t; idx < 832; idx += 256) {
        if (idx < 704) {
            int ch = idx / 22, r = idx - ch * 22;
            *(unsigned int*)&vt[ch * 536 + r * 24 + 22] = 0u;
        } else {
            int k2 = idx - 704;
            int ch = k2 >> 2, e = k2 & 3;
            *(unsigned int*)&vt[ch * 536 + 528 + e * 2] = 0u;
        }
    }
    for (int idx = t; idx < 484 * 4; idx += 256) {
        int pos = idx >> 2, chunk = idx & 3;
        int r = pos / 22, c = pos - r * 22;
        int gh = min(max(h0 + r - 3, 0), HH - 1);
        int gw = min(max(w0 + c - 3, 0), WW - 1);
        bf16x8 v8 = *(const bf16x8*)(V + (pxb + gh * WW + gw) * 256 + co + chunk * 8);
        unsigned short* dp = &vt[(chunk * 8) * 536 + r * 24 + c];
        #pragma unroll
        for (int e = 0; e < 8; ++e) dp[e * 536] = (unsigned short)v8[e];
    }
    __syncthreads();

    const f32x4 z4 = {0.f, 0.f, 0.f, 0.f};
    const int qw  = min(w0 + n, WW - 1);
    const int kc0 = min(max(w0 - 3 + n, 0), WW - 1);
    const int kc1 = min(w0 + 13 + n, WW - 1);
    const bool hi2 = (g >> 1) != 0;
    const int src0 = ((g & 1) * 2) * 16 + n;
    const int src1 = src0 + 16;

    for (int hh = 0; hh < 4; ++hh) {
        const int hl = wv * 4 + hh;
        const int h = h0 + hl;
        const int hc = min(h, HH - 1);

        const bf16x8 qf = *(const bf16x8*)(Q + (pxb + hc * WW + qw) * 256 + co + g * 8);

        f32x4 s0[7], s1[7];
        #pragma unroll
        for (int i = 0; i < 7; ++i) {
            const int gh = min(max(h - 3 + i, 0), HH - 1);
            const unsigned short* kr = K + (pxb + gh * WW) * 256 + co + g * 8;
            bf16x8 a0 = *(const bf16x8*)(kr + (size_t)kc0 * 256);
            bf16x8 a1 = *(const bf16x8*)(kr + (size_t)kc1 * 256);
            s0[i] = __builtin_amdgcn_mfma_f32_16x16x32_bf16(a0, qf, z4, 0, 0, 0);
            s1[i] = __builtin_amdgcn_mfma_f32_16x16x32_bf16(a1, qf, z4, 0, 0, 0);
        }

        float mx = -3.0e38f;
        #pragma unroll
        for (int r = 0; r < 4; ++r) {
            float m0 = s0[0][r], m1 = s1[0][r];
            #pragma unroll
            for (int i = 1; i < 7; ++i) {
                m0 = fmaxf(m0, s0[i][r]);
                m1 = fmaxf(m1, s1[i][r]);
            }
            const int k0 = 4 * g + r, k1 = k0 + 16;
            mx = fmaxf(mx, ((unsigned)(k0 - n) <= 6u) ? m0 : -3.0e38f);
            mx = fmaxf(mx, ((unsigned)(k1 - n) <= 6u) ? m1 : -3.0e38f);
        }
        mx = fmaxf(mx, __shfl_xor(mx, 16));
        mx = fmaxf(mx, __shfl_xor(mx, 32));

        float sum = 0.0f;
        #pragma unroll
        for (int r = 0; r < 4; ++r) {
            const int k0 = 4 * g + r, k1 = k0 + 16;
            const bool in0 = (unsigned)(k0 - n) <= 6u;
            const bool in1 = (unsigned)(k1 - n) <= 6u;
            #pragma unroll
            for (int i = 0; i < 7; ++i) {
                float e0 = in0 ? __expf((s0[i][r] - mx) * 0.17677669529663687f) : 0.0f;
                float e1 = in1 ? __expf((s1[i][r] - mx) * 0.17677669529663687f) : 0.0f;
                s0[i][r] = e0; s1[i][r] = e1;
                sum += e0 + e1;
            }
        }
        sum += __shfl_xor(sum, 16);
        sum += __shfl_xor(sum, 32);
        const float inv = __builtin_amdgcn_rcpf(sum);

        unsigned int pa[7], pb[7], pc[7], pd[7];
        #pragma unroll
        for (int i = 0; i < 7; ++i) {
            pa[i] = cvtpk_bf16(s0[i][0] * inv, s0[i][1] * inv);
            pb[i] = cvtpk_bf16(s0[i][2] * inv, s0[i][3] * inv);
            pc[i] = cvtpk_bf16(s1[i][0] * inv, s1[i][1] * inv);
            pd[i] = cvtpk_bf16(s1[i][2] * inv, s1[i][3] * inv);
        }

        f32x4 acc0 = z4, acc1 = z4;
        #pragma unroll
        for (int i = 0; i < 7; ++i) {
            const int a0s = __shfl((int)pa[i], src0);
            const int c0s = __shfl((int)pc[i], src0);
            const int b0s = __shfl((int)pb[i], src0);
            const int d0s = __shfl((int)pd[i], src0);
            const int a1s = __shfl((int)pa[i], src1);
            const int c1s = __shfl((int)pc[i], src1);
            const int b1s = __shfl((int)pb[i], src1);
            const int d1s = __shfl((int)pd[i], src1);
            union { unsigned int u[4]; bf16x8 v; } pu;
            pu.u[0] = (unsigned int)(hi2 ? c0s : a0s);
            pu.u[1] = (unsigned int)(hi2 ? d0s : b0s);
            pu.u[2] = (unsigned int)(hi2 ? c1s : a1s);
            pu.u[3] = (unsigned int)(hi2 ? d1s : b1s);
            const unsigned short* vr = &vt[(hl + i) * 24 + g * 8];
            bf16x8 vf0 = *(const bf16x8*)(vr + n * 536);
            bf16x8 vf1 = *(const bf16x8*)(vr + (n + 16) * 536);
            acc0 = __builtin_amdgcn_mfma_f32_16x16x32_bf16(pu.v, vf0, acc0, 0, 0, 0);
            acc1 = __builtin_amdgcn_mfma_f32_16x16x32_bf16(pu.v, vf1, acc1, 0, 0, 0);
        }

        if (h < HH) {
            unsigned short* ap = A + (pxb + h * WW) * 256 + co + n;
            const int wp = w0 + g * 4;
            #pragma unroll
            for (int r = 0; r < 4; ++r) {
                if (wp + r < WW) {
                    ap[(size_t)(wp + r) * 256]      = f2bf(acc0[r]);
                    ap[(size_t)(wp + r) * 256 + 16] = f2bf(acc1[r]);
                }
            }
        }
    }
}

// ---------------------------------------------------------------------------
// Workspace (bytes):                                      total 216.6 MB
//   0         : Fl_bf  [80000][64]  bf16   (10.24 MB)
//   10240000  : Fc_bf  [80000][256] bf16   (40.96)  ┐ after proj_ln1 this
//   51200000  : Qb/Ab  [80000][256] bf16   (40.96)  ├ whole 163.84 MB region
//   92160000  : Kb, Vb [2x 40.96]                   ┘ becomes Y1 [80000][1024]
//   174080000 : XLb    [80000][256] bf16   (40.96)
//   215040000 : bf16 weights (~1.5 MB): Wq(16K) Wkv(128K) Wcat(80K) W1t W2t
//   d_out     : final NCHW output only
// ---------------------------------------------------------------------------
extern "C" void kernel_launch(void* const* d_in, const int* in_sizes, int n_in,
                              void* d_out, int out_size, void* d_ws, size_t ws_size,
                              hipStream_t stream)
{
    const float* F_lidar = (const float*)d_in[0];
    const float* F_cam   = (const float*)d_in[1];
    const float* Wq  = (const float*)d_in[2];
    const float* Wk  = (const float*)d_in[3];
    const float* Wv  = (const float*)d_in[4];
    const float* Wo  = (const float*)d_in[5];
    const float* Wr  = (const float*)d_in[6];
    const float* g1  = (const float*)d_in[7];
    const float* b1  = (const float*)d_in[8];
    const float* g2  = (const float*)d_in[9];
    const float* b2  = (const float*)d_in[10];
    const float* W1  = (const float*)d_in[11];
    const float* bf1 = (const float*)d_in[12];
    const float* W2  = (const float*)d_in[13];
    const float* bf2 = (const float*)d_in[14];

    char* wsb = (char*)d_ws;
    unsigned short* Fl  = (unsigned short*)(wsb);
    unsigned short* Fc  = (unsigned short*)(wsb + 10240000);
    unsigned short* Qb  = (unsigned short*)(wsb + 51200000);
    unsigned short* Kb  = (unsigned short*)(wsb + 92160000);
    unsigned short* Vb  = (unsigned short*)(wsb + 133120000);
    unsigned short* Y1b = Fc;                             // [80000][1024] bf16
    unsigned short* XLb = (unsigned short*)(wsb + 174080000);
    unsigned short* Wq_b  = (unsigned short*)(wsb + 215040000);
    unsigned short* Wkv_b = Wq_b + 16384;
    unsigned short* Wcat  = Wkv_b + 131072;
    unsigned short* W1t   = Wcat + 81920;
    unsigned short* W2t   = W1t + 262144;
    float* out = (float*)d_out;

    const dim3 blk(256);

    cvt_weights<<<dim3(1024, 5), blk, 0, stream>>>(Wq, Wk, Wv, Wo, Wr, W1, W2,
        Wq_b, Wkv_b, Wcat, W1t, W2t);
    to_nhwc<<<dim3(625, 1, 2), blk, 0, stream>>>(F_lidar, Fl, 64);
    to_nhwc<<<dim3(625, 4, 2), blk, 0, stream>>>(F_cam, Fc, 256);

    // Q projection
    gemm_bf16<<<dim3(625, 2), blk, 0, stream>>>(Fl, 64, Fl, 64, 64,
        Wq_b, 64, 64, Qb, nullptr, nullptr, nullptr, 4, 256);
    // fused K|V projection: N=512, split output at cout 256
    gemm_bf16<<<dim3(625, 4), blk, 0, stream>>>(Fc, 256, Fc, 256, 256,
        Wkv_b, 256, 256, Kb, Vb, nullptr, nullptr, 4 | 8, 256);

    // attention (A overwrites Q in-place)
    attn_bf16<<<dim3(169, 8, 2), blk, 0, stream>>>(Qb, Kb, Vb, Qb);

    // fused out-proj + residual + LN1 -> XLb (bf16 NHWC)
    proj_ln1<<<dim3(625), dim3(512), 0, stream>>>(Qb, Fl, Wcat, g1, b1, XLb);

    // FFN half 1: full-width hidden, one dispatch (relu + bias), Y1 bf16
    gemm_bf16<<<dim3(625, 8), blk, 0, stream>>>(XLb, 256, XLb, 256, 256,
        W1t, 256, 256, Y1b, nullptr, nullptr, bf1, 5, 1024);

    // FFN half 2 fused with residual + LN2 + NCHW write
    ffn2_ln2<<<dim3(625), dim3(512), 0, stream>>>(Y1b, XLb, W2t, bf2, g2, b2, out);
}